// Round 10
// baseline (209.439 us; speedup 1.0000x reference)
//
#include <hip/hip_runtime.h>
#include <hip/hip_fp16.h>

#define IN_DIM 128
#define HID 64
#define HEADS 4
#define OUT_DIM 40
#define CAP 64
#define NEG 0.2f
#define PA_EPB 4096     // edges per Phase-A block
#define BKT_SH 9        // 512 dsts per bucket
#define BKT_CAP 10240   // edge capacity per bucket region
#define GPAD 264        // padded LDS row stride (halfs) for gtile
#define HGP 72          // h0L row stride in halfs

__device__ __forceinline__ float lrelu(float v) { return v > 0.f ? v : NEG * v; }

union HU { float2 f2; __half2 h2[2]; };
union HU2 { float4 f4; __half2 h2[4]; };

typedef _Float16 f16x8 __attribute__((ext_vector_type(8)));
typedef float f32x4 __attribute__((ext_vector_type(4)));
union FU { float4 f4; f16x8 v; };

__device__ __forceinline__ float4 unpack_h4(float2 bits) {
    HU u; u.f2 = bits;
    float2 lo = __half22float2(u.h2[0]);
    float2 hi = __half22float2(u.h2[1]);
    return make_float4(lo.x, lo.y, hi.x, hi.y);
}

// ---------- Phase A (R4-verbatim): bucket-binning + prep tail ----------
__global__ __launch_bounds__(256) void partA_kernel(
    const int* __restrict__ ei, int E, int nbkt, int paBlocks,
    int* __restrict__ cnt, unsigned int* __restrict__ ebuf,
    const float* __restrict__ Wg, const float* __restrict__ attS,
    const float* __restrict__ attD, const float* __restrict__ Wc,
    const float* __restrict__ Wp,
    __half* __restrict__ WgT, __half* __restrict__ WcTg,
    __half* __restrict__ WpT, __half* __restrict__ BsdT)
{
    if (blockIdx.x >= paBlocks) {
        int gid = (blockIdx.x - paBlocks) * 256 + threadIdx.x;
        if (gid < 16384) {                        // WgT[o][k] = Wg[k][o]
            int o = gid >> 6, k = gid & 63;
            WgT[gid] = __float2half(Wg[k * 256 + o]);
        } else if (gid < 26624) {                 // WcTg[o][k] = Wc[k][o]
            int i = gid - 16384;
            int o = i >> 8, k = i & 255;
            WcTg[i] = __float2half(Wc[k * OUT_DIM + o]);
        } else if (gid < 34816) {                 // WpT[o][k] = Wp[k][o]
            int i = gid - 26624;
            int o = i >> 7, k = i & 127;
            WpT[i] = __float2half(Wp[k * HID + o]);
        } else if (gid < 35840) {                 // BsdT folded S/D B-matrix
            int i = gid - 34816;
            int n2 = i >> 6, k = i & 63;
            float v = 0.f;
            if (n2 < 8) {
                int hd = n2 & 3;
                const float* wr = Wg + k * 256 + hd * 64;
                const float* av = (n2 < 4) ? (attS + hd * 64) : (attD + hd * 64);
                for (int c = 0; c < 64; ++c) v += wr[c] * av[c];
            }
            BsdT[i] = __float2half(v);
        }
        return;
    }

    __shared__ int localCnt[128];
    __shared__ int baseArr[128];
    for (int i = threadIdx.x; i < nbkt; i += 256) localCnt[i] = 0;
    __syncthreads();

    const int e0 = blockIdx.x * PA_EPB + threadIdx.x;
    unsigned short l[16];
#pragma unroll
    for (int j = 0; j < 16; ++j) {
        int e = e0 + j * 256;
        if (e < E) {
            int d = ei[E + e];
            l[j] = (unsigned short)atomicAdd(&localCnt[d >> BKT_SH], 1);
        }
    }
    __syncthreads();
    for (int i = threadIdx.x; i < nbkt; i += 256)
        baseArr[i] = atomicAdd(&cnt[i], localCnt[i]);
    __syncthreads();
#pragma unroll
    for (int j = 0; j < 16; ++j) {
        int e = e0 + j * 256;
        if (e < E) {
            int s = ei[e];
            int d = ei[E + e];
            int b = d >> BKT_SH;
            int off = baseArr[b] + (int)l[j];
            if (off < BKT_CAP)
                ebuf[(size_t)b * BKT_CAP + off] =
                    ((unsigned)(d & ((1 << BKT_SH) - 1)) << 16) | (unsigned)s;
        }
    }
}

// ---------- Merged Phase B (lite) + MFMA-proj (R4-verbatim) ----------
__global__ __launch_bounds__(256) void partBproj_kernel(
    const unsigned int* __restrict__ ebuf, const int* __restrict__ cnt,
    int* __restrict__ deg, unsigned short* __restrict__ csr, int nbkt,
    const float* __restrict__ x, const __half* __restrict__ WpT,
    const float* __restrict__ bp, const float* __restrict__ temb,
    const int* __restrict__ ts, const __half* __restrict__ BsdT,
    __half* __restrict__ h0h, float* __restrict__ aS, float* __restrict__ aD, int N)
{
    __shared__ __align__(16) char smem[32 * HGP * 2];  // 4.6 KB union

    if ((int)blockIdx.x < nbkt) {
        int* cntL = (int*)smem;
        const int b = blockIdx.x;
        for (int i = threadIdx.x; i < 512; i += 256) cntL[i] = 0;
        __syncthreads();

        int cb = cnt[b]; cb = cb < BKT_CAP ? cb : BKT_CAP;
        const unsigned int* eb = ebuf + (size_t)b * BKT_CAP;
        const int d0 = b << BKT_SH;
        for (int i = threadIdx.x; i < cb; i += 256) {
            unsigned v = eb[i];
            int dloc = v >> 16;
            int slot = atomicAdd(&cntL[dloc], 1);
            if (slot < CAP)
                csr[((size_t)(d0 + dloc) << 6) + slot] = (unsigned short)(v & 0xFFFFu);
        }
        __syncthreads();
        for (int i = threadIdx.x; i < 512; i += 256) {
            int d = d0 + i;
            if (d < N) deg[d] = cntL[i];
        }
        return;
    }

    __half* h0L = (__half*)smem;
    const int t = threadIdx.x;
    const int lane = t & 63, wq = t >> 6;
    const int m16 = lane & 15, quad = lane >> 4;
    const int mt = wq >> 1;
    const int ntb = (wq & 1) * 2;
    const int nodeBase = ((int)blockIdx.x - nbkt) * 32;

    f32x4 acc[2];
    acc[0] = (f32x4){0.f, 0.f, 0.f, 0.f};
    acc[1] = (f32x4){0.f, 0.f, 0.f, 0.f};

    {
        int n = nodeBase + mt * 16 + m16; n = n < N ? n : N - 1;
        const float* xr = x + (size_t)n * IN_DIM;
#pragma unroll
        for (int ks = 0; ks < 4; ++ks) {
            float4 xa = *(const float4*)(xr + ks * 32 + quad * 8);
            float4 xb = *(const float4*)(xr + ks * 32 + quad * 8 + 4);
            HU2 u;
            u.h2[0] = __floats2half2_rn(xa.x, xa.y);
            u.h2[1] = __floats2half2_rn(xa.z, xa.w);
            u.h2[2] = __floats2half2_rn(xb.x, xb.y);
            u.h2[3] = __floats2half2_rn(xb.z, xb.w);
            FU a; a.f4 = u.f4;
#pragma unroll
            for (int q = 0; q < 2; ++q) {
                int o = (ntb + q) * 16 + m16;
                FU b; b.f4 = *(const float4*)(WpT + o * IN_DIM + ks * 32 + quad * 8);
                acc[q] = __builtin_amdgcn_mfma_f32_16x16x32_f16(a.v, b.v, acc[q], 0, 0, 0);
            }
        }
    }

    {
        float bv[2];
#pragma unroll
        for (int q = 0; q < 2; ++q) bv[q] = bp[(ntb + q) * 16 + m16];
#pragma unroll
        for (int r = 0; r < 4; ++r) {
            int nloc = mt * 16 + quad * 4 + r;
            int n = nodeBase + nloc;
            if (n < N) {
                int tv = ts[n];
                const float* te = temb + (size_t)tv * HID;
#pragma unroll
                for (int q = 0; q < 2; ++q) {
                    int c = (ntb + q) * 16 + m16;
                    float v = fmaxf(acc[q][r] + bv[q], 0.f) + te[c];
                    h0L[nloc * HGP + c] = __float2half(v);
                }
            }
        }
    }
    __syncthreads();

    {
        int row = t >> 3, ch = (t & 7) * 8;
        int n = nodeBase + row;
        if (n < N)
            *(float4*)(h0h + (size_t)n * HID + ch) = *(const float4*)(h0L + row * HGP + ch);
    }

    if (wq < 2) {
        f32x4 acc2 = (f32x4){0.f, 0.f, 0.f, 0.f};
#pragma unroll
        for (int ks = 0; ks < 2; ++ks) {
            FU a; a.f4 = *(const float4*)(h0L + (wq * 16 + m16) * HGP + ks * 32 + quad * 8);
            FU b; b.f4 = *(const float4*)(BsdT + m16 * 64 + ks * 32 + quad * 8);
            acc2 = __builtin_amdgcn_mfma_f32_16x16x32_f16(a.v, b.v, acc2, 0, 0, 0);
        }
#pragma unroll
        for (int r = 0; r < 4; ++r) {
            int n = nodeBase + wq * 16 + quad * 4 + r;
            if (n < N) {
                if (m16 < 4)      aS[n * 4 + m16]       = acc2[r];
                else if (m16 < 8) aD[n * 4 + (m16 - 4)] = acc2[r];
            }
        }
    }
}

// ---------- agg: 1 wave/node; float2 (8B/lane) gather — 4 rows per load instr,
//            half the load count and 2x rows-in-flight vs the half2 version.
//            Lane layout: rg = lane>>4 (row group), lc = lane&15 (channel quad).
//            Final xor-16/32 reduce over row groups; 16 lanes write float2. ----------
__global__ __launch_bounds__(256) void agg_kernel(
    const __half* __restrict__ h0h, const float* __restrict__ aS,
    const float* __restrict__ aD, const int* __restrict__ deg,
    const unsigned short* __restrict__ csr, __half* __restrict__ agg0h, int N)
{
    __shared__ float p_lds[4 * CAP * HEADS];  // 4 KB
    __shared__ int   s_lds[4 * CAP];          // 1 KB

    const int t = threadIdx.x;
    const int lane = t & 63, wq = t >> 6;
    const int n = blockIdx.x * 4 + wq;
    if (n >= N) return;
    const int hd16 = lane >> 4, li = lane & 15;

    const float adn = aD[n * 4 + hd16];
    const float es = lrelu(aS[n * 4 + hd16] + adn);

    int dn = deg[n]; dn = dn < CAP ? dn : CAP;
    const unsigned short* cs = csr + (size_t)n * CAP;
    float* pL = p_lds + wq * CAP * HEADS;
    int*   sL = s_lds + wq * CAP;

    float m = -1e30f;
    for (int i = li; i < dn; i += 16) {
        int src = cs[i];
        if (hd16 == 0) sL[i] = src << 7;
        float e = lrelu(aS[src * 4 + hd16] + adn);
        pL[i * HEADS + hd16] = e;
        m = fmaxf(m, e);
    }
#pragma unroll
    for (int off = 8; off > 0; off >>= 1)
        m = fmaxf(m, __shfl_xor(m, off));
    m = fmaxf(m, es);
    float mh[4], esh[4];
#pragma unroll
    for (int h = 0; h < 4; ++h) {
        mh[h]  = __shfl(m, h * 16);
        esh[h] = __shfl(es, h * 16);
    }

    float sp = 0.f;
    for (int idx = lane; idx < dn * 4; idx += 64) {
        float p = __expf(pL[idx] - mh[idx & 3]);
        pL[idx] = p;
        sp += p;
    }
#pragma unroll
    for (int off = 4; off < 64; off <<= 1)
        sp += __shfl_xor(sp, off);
    float pselfh[4], invh[4];
#pragma unroll
    for (int h = 0; h < 4; ++h) {
        float sh = __shfl(sp, h);
        pselfh[h] = __expf(esh[h] - mh[h]);
        invh[h] = 1.f / (sh + pselfh[h] + 1e-16f);
    }

    // ---- gather-accumulate: rg = row group (0-3), lc = channel quad ----
    const int rg = hd16;            // lane >> 4
    const int lc = li;              // lane & 15
    const char* hb = (const char*)h0h;
    const int laneByte = lc << 3;   // 8 B per lane

    float4 acc[4];
    {
        float4 f = make_float4(0.f, 0.f, 0.f, 0.f);
        if (rg == 0)
            f = unpack_h4(*(const float2*)(hb + ((size_t)n << 7) + laneByte));
#pragma unroll
        for (int h = 0; h < 4; ++h) {
            acc[h].x = pselfh[h] * f.x;
            acc[h].y = pselfh[h] * f.y;
            acc[h].z = pselfh[h] * f.z;
            acc[h].w = pselfh[h] * f.w;
        }
    }
    int i = 0;
    for (; i + 8 <= dn; i += 8) {
        int offA = sL[i + rg];
        int offB = sL[i + 4 + rg];
        float2 vA = *(const float2*)(hb + offA + laneByte);
        float2 vB = *(const float2*)(hb + offB + laneByte);
        float4 pA = *(const float4*)(pL + (i + rg) * 4);
        float4 pB = *(const float4*)(pL + (i + 4 + rg) * 4);
        float4 fA = unpack_h4(vA);
        float4 fB = unpack_h4(vB);
        acc[0].x += pA.x * fA.x; acc[0].y += pA.x * fA.y; acc[0].z += pA.x * fA.z; acc[0].w += pA.x * fA.w;
        acc[1].x += pA.y * fA.x; acc[1].y += pA.y * fA.y; acc[1].z += pA.y * fA.z; acc[1].w += pA.y * fA.w;
        acc[2].x += pA.z * fA.x; acc[2].y += pA.z * fA.y; acc[2].z += pA.z * fA.z; acc[2].w += pA.z * fA.w;
        acc[3].x += pA.w * fA.x; acc[3].y += pA.w * fA.y; acc[3].z += pA.w * fA.z; acc[3].w += pA.w * fA.w;
        acc[0].x += pB.x * fB.x; acc[0].y += pB.x * fB.y; acc[0].z += pB.x * fB.z; acc[0].w += pB.x * fB.w;
        acc[1].x += pB.y * fB.x; acc[1].y += pB.y * fB.y; acc[1].z += pB.y * fB.z; acc[1].w += pB.y * fB.w;
        acc[2].x += pB.z * fB.x; acc[2].y += pB.z * fB.y; acc[2].z += pB.z * fB.z; acc[2].w += pB.z * fB.w;
        acc[3].x += pB.w * fB.x; acc[3].y += pB.w * fB.y; acc[3].z += pB.w * fB.z; acc[3].w += pB.w * fB.w;
    }
    for (; i + 4 <= dn; i += 4) {
        int off = sL[i + rg];
        float2 v = *(const float2*)(hb + off + laneByte);
        float4 p = *(const float4*)(pL + (i + rg) * 4);
        float4 f = unpack_h4(v);
        acc[0].x += p.x * f.x; acc[0].y += p.x * f.y; acc[0].z += p.x * f.z; acc[0].w += p.x * f.w;
        acc[1].x += p.y * f.x; acc[1].y += p.y * f.y; acc[1].z += p.y * f.z; acc[1].w += p.y * f.w;
        acc[2].x += p.z * f.x; acc[2].y += p.z * f.y; acc[2].z += p.z * f.z; acc[2].w += p.z * f.w;
        acc[3].x += p.w * f.x; acc[3].y += p.w * f.y; acc[3].z += p.w * f.z; acc[3].w += p.w * f.w;
    }
    if (i < dn && rg < dn - i) {  // tail rows: only participating row groups
        int off = sL[i + rg];
        float2 v = *(const float2*)(hb + off + laneByte);
        float4 p = *(const float4*)(pL + (i + rg) * 4);
        float4 f = unpack_h4(v);
        acc[0].x += p.x * f.x; acc[0].y += p.x * f.y; acc[0].z += p.x * f.z; acc[0].w += p.x * f.w;
        acc[1].x += p.y * f.x; acc[1].y += p.y * f.y; acc[1].z += p.y * f.z; acc[1].w += p.y * f.w;
        acc[2].x += p.z * f.x; acc[2].y += p.z * f.y; acc[2].z += p.z * f.z; acc[2].w += p.z * f.w;
        acc[3].x += p.w * f.x; acc[3].y += p.w * f.y; acc[3].z += p.w * f.z; acc[3].w += p.w * f.w;
    }
    // reduce over the 4 row groups
#pragma unroll
    for (int h = 0; h < 4; ++h) {
        acc[h].x += __shfl_xor(acc[h].x, 16); acc[h].x += __shfl_xor(acc[h].x, 32);
        acc[h].y += __shfl_xor(acc[h].y, 16); acc[h].y += __shfl_xor(acc[h].y, 32);
        acc[h].z += __shfl_xor(acc[h].z, 16); acc[h].z += __shfl_xor(acc[h].z, 32);
        acc[h].w += __shfl_xor(acc[h].w, 16); acc[h].w += __shfl_xor(acc[h].w, 32);
    }
    if (lane < 16) {
#pragma unroll
        for (int h = 0; h < 4; ++h) {
            HU u;
            u.h2[0] = __floats2half2_rn(acc[h].x * invh[h], acc[h].y * invh[h]);
            u.h2[1] = __floats2half2_rn(acc[h].z * invh[h], acc[h].w * invh[h]);
            *(float2*)(agg0h + (size_t)n * 256 + h * 64 + lc * 4) = u.f2;
        }
    }
}

// ---------- gatcls (R4-verbatim) ----------
__global__ __launch_bounds__(256) void gatcls_kernel(
    const __half* __restrict__ agg0h, const __half* __restrict__ WgT,
    const float* __restrict__ bg, const __half* __restrict__ WcTg,
    const float* __restrict__ bc, float* __restrict__ out, int N)
{
    __shared__ __half gtile[32 * GPAD];

    const int t = threadIdx.x;
    const int lane = t & 63, wq = t >> 6;
    const int m16 = lane & 15, quad = lane >> 4;
    const int nodeBase = blockIdx.x * 32;

    {
        const int h = wq;
        f32x4 acc[2][4];
#pragma unroll
        for (int mt = 0; mt < 2; ++mt)
#pragma unroll
            for (int nt = 0; nt < 4; ++nt)
                acc[mt][nt] = (f32x4){0.f, 0.f, 0.f, 0.f};

#pragma unroll
        for (int ks = 0; ks < 2; ++ks) {
            FU a[2], b[4];
#pragma unroll
            for (int mt = 0; mt < 2; ++mt) {
                int n = nodeBase + mt * 16 + m16; n = n < N ? n : N - 1;
                a[mt].f4 = *(const float4*)(agg0h + (size_t)n * 256 + h * 64 + ks * 32 + quad * 8);
            }
#pragma unroll
            for (int nt = 0; nt < 4; ++nt) {
                int o = h * 64 + nt * 16 + m16;
                b[nt].f4 = *(const float4*)(WgT + o * 64 + ks * 32 + quad * 8);
            }
#pragma unroll
            for (int mt = 0; mt < 2; ++mt)
#pragma unroll
                for (int nt = 0; nt < 4; ++nt)
                    acc[mt][nt] = __builtin_amdgcn_mfma_f32_16x16x32_f16(
                        a[mt].v, b[nt].v, acc[mt][nt], 0, 0, 0);
        }
#pragma unroll
        for (int nt = 0; nt < 4; ++nt) {
            int o = h * 64 + nt * 16 + m16;
            float bv = bg[o];
#pragma unroll
            for (int mt = 0; mt < 2; ++mt) {
#pragma unroll
                for (int r = 0; r < 4; ++r) {
                    int nloc = mt * 16 + quad * 4 + r;
                    gtile[nloc * GPAD + o] = __float2half(fmaxf(acc[mt][nt][r] + bv, 0.f));
                }
            }
        }
    }
    __syncthreads();

    {
        const int mt = wq >> 1;
        const int ntCount = (wq & 1) ? 1 : 2;
        const int ntBase = (wq & 1) ? 2 : 0;
        f32x4 acc2[2];
        acc2[0] = (f32x4){0.f, 0.f, 0.f, 0.f};
        acc2[1] = (f32x4){0.f, 0.f, 0.f, 0.f};
#pragma unroll
        for (int ks = 0; ks < 8; ++ks) {
            FU a; a.f4 = *(const float4*)(gtile + (mt * 16 + m16) * GPAD + ks * 32 + quad * 8);
            for (int q = 0; q < ntCount; ++q) {
                int o = (ntBase + q) * 16 + m16;
                int oc = o < OUT_DIM ? o : OUT_DIM - 1;
                FU b; b.f4 = *(const float4*)(WcTg + oc * 256 + ks * 32 + quad * 8);
                acc2[q] = __builtin_amdgcn_mfma_f32_16x16x32_f16(a.v, b.v, acc2[q], 0, 0, 0);
            }
        }
        for (int q = 0; q < ntCount; ++q) {
            int o = (ntBase + q) * 16 + m16;
            if (o < OUT_DIM) {
                float bv = bc[o];
#pragma unroll
                for (int r = 0; r < 4; ++r) {
                    int n = nodeBase + mt * 16 + quad * 4 + r;
                    if (n < N) out[(size_t)n * OUT_DIM + o] = acc2[q][r] + bv;
                }
            }
        }
    }
}

extern "C" void kernel_launch(void* const* d_in, const int* in_sizes, int n_in,
                              void* d_out, int out_size, void* d_ws, size_t ws_size,
                              hipStream_t stream) {
    const float* x    = (const float*)d_in[0];
    const int*   ei   = (const int*)d_in[1];
    const int*   ts   = (const int*)d_in[2];
    const float* Wp   = (const float*)d_in[3];
    const float* bp   = (const float*)d_in[4];
    const float* temb = (const float*)d_in[5];
    const float* Wg   = (const float*)d_in[6];
    const float* attS = (const float*)d_in[7];
    const float* attD = (const float*)d_in[8];
    const float* bg   = (const float*)d_in[9];
    const float* Wc   = (const float*)d_in[10];
    const float* bc   = (const float*)d_in[11];
    float* out = (float*)d_out;

    const int N = in_sizes[0] / IN_DIM;   // 50000
    const int E = in_sizes[1] / 2;        // 800000
    const int nbkt = (N + (1 << BKT_SH) - 1) >> BKT_SH;  // 98

    char* w = (char*)d_ws;
    __half*         h0h   = (__half*)w;         w += (size_t)N * HID * 2;
    __half*         agg0h = (__half*)w;         w += (size_t)N * 256 * 2;
    float*          aS    = (float*)w;          w += (size_t)N * HEADS * 4;
    float*          aD    = (float*)w;          w += (size_t)N * HEADS * 4;
    int*            deg   = (int*)w;            w += (size_t)N * 4;
    unsigned short* csr   = (unsigned short*)w; w += (size_t)N * CAP * 2;
    unsigned int*   ebuf  = (unsigned int*)w;   w += (size_t)nbkt * BKT_CAP * 4;
    int*            cnt   = (int*)w;            w += (size_t)nbkt * 4;
    __half*         WgT   = (__half*)w;         w += (size_t)256 * HID * 2;
    __half*         WcTg  = (__half*)w;         w += (size_t)OUT_DIM * 256 * 2;
    __half*         WpT   = (__half*)w;         w += (size_t)HID * IN_DIM * 2;
    __half*         BsdT  = (__half*)w;         w += (size_t)16 * HID * 2;

    const int paBlocks  = (E + PA_EPB - 1) / PA_EPB;   // 196
    const int prepWork  = 35840;
    const int prepBlocks = (prepWork + 255) / 256;     // 140
    const int projBlocks = (N + 31) / 32;              // 1563

    hipMemsetAsync(cnt, 0, (size_t)nbkt * 4, stream);
    partA_kernel<<<paBlocks + prepBlocks, 256, 0, stream>>>(
        ei, E, nbkt, paBlocks, cnt, ebuf, Wg, attS, attD, Wc, Wp,
        WgT, WcTg, WpT, BsdT);
    partBproj_kernel<<<nbkt + projBlocks, 256, 0, stream>>>(
        ebuf, cnt, deg, csr, nbkt, x, WpT, bp, temb, ts, BsdT, h0h, aS, aD, N);
    agg_kernel<<<(N + 3) / 4, 256, 0, stream>>>(h0h, aS, aD, deg, csr, agg0h, N);
    gatcls_kernel<<<(N + 31) / 32, 256, 0, stream>>>(agg0h, WgT, bg, WcTg, bc, out, N);
}